// Round 3
// baseline (480.514 us; speedup 1.0000x reference)
//
#include <hip/hip_runtime.h>
#include <math.h>

#define NEG_SLOPE 0.2f

typedef __attribute__((ext_vector_type(8))) short short8;
typedef __attribute__((ext_vector_type(4))) float f32x4;

__device__ __forceinline__ float lrelu(float x) { return x > 0.f ? x : NEG_SLOPE * x; }
__device__ __forceinline__ float eluf(float x) { return x > 0.f ? x : expm1f(x); }
__device__ __forceinline__ unsigned short f2b(float f) {
  unsigned int u = __float_as_uint(f);
  u += 0x7FFFu + ((u >> 16) & 1u);  // RNE
  return (unsigned short)(u >> 16);
}
__device__ __forceinline__ float b2f(unsigned short h) {
  return __uint_as_float(((unsigned int)h) << 16);
}

// ---------------- casts
__global__ __launch_bounds__(256) void cast_bf16_vec(const float* __restrict__ in,
                                                     unsigned short* __restrict__ out, int n4) {
  int i = blockIdx.x * 256 + threadIdx.x;
  if (i < n4) {
    float4 v = *(const float4*)(in + (size_t)i * 4);
    ushort4 o;
    o.x = f2b(v.x); o.y = f2b(v.y); o.z = f2b(v.z); o.w = f2b(v.w);
    *(ushort4*)(out + (size_t)i * 4) = o;
  }
}

// W1 [128][256], W2 [256][256] fp32 -> transposed bf16 [256][K]
__global__ __launch_bounds__(256) void cast_w_both(const float* __restrict__ W1,
                                                   unsigned short* __restrict__ W1t,
                                                   const float* __restrict__ W2,
                                                   unsigned short* __restrict__ W2t) {
  int id = blockIdx.x * 256 + threadIdx.x;
  if (id < 128 * 256) {
    int k = id >> 8, n = id & 255;
    W1t[(size_t)n * 128 + k] = f2b(W1[id]);
  } else {
    int j = id - 128 * 256;
    if (j < 256 * 256) {
      int k = j >> 8, n = j & 255;
      W2t[(size_t)n * 256 + k] = f2b(W2[j]);
    }
  }
}

// ---------------- bf16 MFMA GEMM: C[M][256] = A[M][K] @ B, B given transposed Bt[256][K].
#define BM 128
#define BN 64
#define BK 32
#define LDK 40
__global__ __launch_bounds__(256) void gemm_bf16(const unsigned short* __restrict__ A,
                                                 const unsigned short* __restrict__ Bt,
                                                 unsigned short* __restrict__ C, int M, int K) {
  __shared__ unsigned short As[BM][LDK];
  __shared__ unsigned short Bs[BN][LDK];
  const int tid = threadIdx.x;
  const int wave = tid >> 6, lane = tid & 63;
  const int quad = lane >> 4, l16 = lane & 15;
  const int row0 = blockIdx.x * BM;
  const int col0 = blockIdx.y * BN;

  f32x4 zero = {0.f, 0.f, 0.f, 0.f};
  f32x4 acc[2][4];
#pragma unroll
  for (int mt = 0; mt < 2; ++mt)
#pragma unroll
    for (int nt = 0; nt < 4; ++nt) acc[mt][nt] = zero;

  for (int kk = 0; kk < K; kk += BK) {
#pragma unroll
    for (int l = 0; l < 2; ++l) {
      int idx = tid + l * 256;
      int r = idx >> 2, ch = (idx & 3) * 8;
      short8 v = {};
      if (row0 + r < M) v = *(const short8*)(A + (size_t)(row0 + r) * K + kk + ch);
      *(short8*)&As[r][ch] = v;
    }
    {
      int n = tid >> 2, ch = (tid & 3) * 8;
      *(short8*)&Bs[n][ch] = *(const short8*)(Bt + (size_t)(col0 + n) * K + kk + ch);
    }
    __syncthreads();
    short8 af[2], bfr[4];
#pragma unroll
    for (int mt = 0; mt < 2; ++mt) af[mt] = *(short8*)&As[wave * 32 + mt * 16 + l16][quad * 8];
#pragma unroll
    for (int nt = 0; nt < 4; ++nt) bfr[nt] = *(short8*)&Bs[nt * 16 + l16][quad * 8];
#pragma unroll
    for (int mt = 0; mt < 2; ++mt)
#pragma unroll
      for (int nt = 0; nt < 4; ++nt)
        acc[mt][nt] = __builtin_amdgcn_mfma_f32_16x16x32_bf16(af[mt], bfr[nt], acc[mt][nt], 0, 0, 0);
    __syncthreads();
  }
#pragma unroll
  for (int mt = 0; mt < 2; ++mt) {
#pragma unroll
    for (int reg = 0; reg < 4; ++reg) {
      int r = row0 + wave * 32 + mt * 16 + quad * 4 + reg;
      if (r < M) {
#pragma unroll
        for (int nt = 0; nt < 4; ++nt)
          C[(size_t)r * 256 + col0 + nt * 16 + l16] = f2b(acc[mt][nt][reg]);
      }
    }
  }
}

// ---------------- el/er from bf16 feat. One wave per node.
__global__ __launch_bounds__(256) void compute_elr(const unsigned short* __restrict__ feat,
                                                   const float* __restrict__ al,
                                                   const float* __restrict__ ar,
                                                   float* __restrict__ el,
                                                   float* __restrict__ er, int N) {
  int wave = threadIdx.x >> 6, lane = threadIdx.x & 63;
  int n = blockIdx.x * 4 + wave;
  if (n >= N) return;
  ushort4 fu = *(const ushort4*)(feat + (size_t)n * 256 + lane * 4);
  float4 a = *(const float4*)(al + lane * 4);
  float4 b = *(const float4*)(ar + lane * 4);
  float f0 = b2f(fu.x), f1 = b2f(fu.y), f2 = b2f(fu.z), f3 = b2f(fu.w);
  float sl = f0 * a.x + f1 * a.y + f2 * a.z + f3 * a.w;
  float sr = f0 * b.x + f1 * b.y + f2 * b.z + f3 * b.w;
#pragma unroll
  for (int d = 1; d < 8; d <<= 1) {
    sl += __shfl_xor(sl, d);
    sr += __shfl_xor(sr, d);
  }
  if ((lane & 7) == 0) {
    el[n * 8 + (lane >> 3)] = sl;
    er[n * 8 + (lane >> 3)] = sr;
  }
}

// ---------------- CSR build
__global__ void deg_count(const int* __restrict__ dst, int* __restrict__ deg, int E) {
  int i = blockIdx.x * blockDim.x + threadIdx.x;
  if (i < E) atomicAdd(&deg[dst[i]], 1);
}

__global__ __launch_bounds__(256) void scan1(const int* __restrict__ deg, int* __restrict__ offs,
                                             int* __restrict__ bsums, int n) {
  __shared__ int sh[256];
  int i = blockIdx.x * 256 + threadIdx.x;
  int v = (i < n) ? deg[i] : 0;
  sh[threadIdx.x] = v;
  __syncthreads();
  for (int d = 1; d < 256; d <<= 1) {
    int t = (threadIdx.x >= d) ? sh[threadIdx.x - d] : 0;
    __syncthreads();
    sh[threadIdx.x] += t;
    __syncthreads();
  }
  if (i < n) offs[i + 1] = sh[threadIdx.x];
  if (threadIdx.x == 255) bsums[blockIdx.x] = sh[255];
  if (i == 0) offs[0] = 0;
}

__global__ __launch_bounds__(256) void scan2(int* __restrict__ bsums, int nb) {
  __shared__ int sh[256];
  int t = threadIdx.x;
  int v = (t < nb) ? bsums[t] : 0;
  sh[t] = v;
  __syncthreads();
  for (int d = 1; d < 256; d <<= 1) {
    int tmp = (t >= d) ? sh[t - d] : 0;
    __syncthreads();
    sh[t] += tmp;
    __syncthreads();
  }
  if (t < nb) bsums[t] = (t == 0) ? 0 : sh[t - 1];
}

// also writes cursor = final offsets (replaces D2D copy)
__global__ __launch_bounds__(256) void scan3(int* __restrict__ offs, const int* __restrict__ bsums,
                                             int* __restrict__ cursor, int n) {
  int i = blockIdx.x * 256 + threadIdx.x;
  if (i < n) {
    int v = offs[i + 1] + bsums[blockIdx.x];
    offs[i + 1] = v;
    cursor[i + 1] = v;
  }
  if (i == 0) cursor[0] = 0;
}

__global__ void scatter_edges(const int* __restrict__ src, const int* __restrict__ dst,
                              int* __restrict__ cursor, int* __restrict__ csrc, int E) {
  int i = blockIdx.x * blockDim.x + threadIdx.x;
  if (i < E) {
    int d = dst[i];
    int pos = atomicAdd(&cursor[d], 1);
    csrc[pos] = src[i];
  }
}

// ---------------- GAT aggregation: one wave per dst node, LDS-staged alpha.
__global__ __launch_bounds__(256) void gat_agg(const int* __restrict__ offs,
                                               const int* __restrict__ csrc,
                                               const unsigned short* __restrict__ feat,
                                               const float* __restrict__ el,
                                               const float* __restrict__ er,
                                               const float* __restrict__ bias,
                                               const unsigned short* __restrict__ hres,
                                               unsigned short* __restrict__ hout,
                                               float* __restrict__ partial, int N, int mode) {
  __shared__ float sh_alpha[4][64 * 8];
  __shared__ int sh_sidx[4][64];
  __shared__ float psum[4][256];
  const int wave = threadIdx.x >> 6;
  const int lane = threadIdx.x & 63;
  const int hh = lane & 7;     // head (stats / alpha phases)
  const int slot = lane >> 3;  // edge slot (stats / alpha phases)
  const int epair = lane >> 5; // accumulate: which edge of the pair
  const int l32 = lane & 31;   // accumulate: feature block l32*8 .. +7
  const int ah = l32 >> 2;     // accumulate: head of my feature block

  // bias for my 8 features (lanes 0..31 use it)
  float bv[8];
  {
    float4 blo = *(const float4*)(bias + l32 * 8);
    float4 bhi = *(const float4*)(bias + l32 * 8 + 4);
    bv[0] = blo.x; bv[1] = blo.y; bv[2] = blo.z; bv[3] = blo.w;
    bv[4] = bhi.x; bv[5] = bhi.y; bv[6] = bhi.z; bv[7] = bhi.w;
  }
  float t[8] = {};

  for (int n = blockIdx.x * 4 + wave; n < N; n += gridDim.x * 4) {
    const int o0 = offs[n];
    const int deg = offs[n + 1] - o0;
    const float er_h = er[n * 8 + hh];

    // ---- pass 1: online softmax stats (8 edge-slots x 8 heads)
    float m = -1e30f, ssum = 0.f;
    for (int base = 0; base < deg; base += 8) {
      int idx = base + slot;
      if (idx < deg) {
        int s = csrc[o0 + idx];
        float e = lrelu(el[s * 8 + hh] + er_h);
        float mn = fmaxf(m, e);
        ssum = ssum * __expf(m - mn) + __expf(e - mn);
        m = mn;
      }
    }
#pragma unroll
    for (int d = 8; d < 64; d <<= 1) {
      float mo = __shfl_xor(m, d);
      float so = __shfl_xor(ssum, d);
      float mn = fmaxf(m, mo);
      ssum = ssum * __expf(m - mn) + so * __expf(mo - mn);
      m = mn;
    }
    float inv_denom = (ssum > 0.f) ? 1.f / ssum : 0.f;

    // ---- pass 2: chunks of <=64 edges: stage alpha+src in LDS, then accumulate
    float acc[8] = {};
    for (int cb = 0; cb < deg; cb += 64) {
      const int ccnt = min(64, deg - cb);
      __builtin_amdgcn_wave_barrier();
      for (int it = 0; it * 8 < ccnt; ++it) {
        int idx = it * 8 + slot;  // local slot < 64
        int g = cb + idx;
        int s = 0;
        float e = -1e30f;
        if (g < deg) {
          s = csrc[o0 + g];
          e = lrelu(el[s * 8 + hh] + er_h);
        }
        if (hh == 0) sh_sidx[wave][idx] = s;
        sh_alpha[wave][idx * 8 + hh] = __expf(e - m) * inv_denom;
      }
      __builtin_amdgcn_wave_barrier();
      for (int j = 0; j < ccnt; j += 2) {
        int eidx = j + epair;
        int s = sh_sidx[wave][eidx];
        float am = sh_alpha[wave][eidx * 8 + ah];
        short8 f = *(const short8*)(feat + (size_t)s * 256 + l32 * 8);
#pragma unroll
        for (int k = 0; k < 8; ++k)
          acc[k] = fmaf(am, b2f((unsigned short)f[k]), acc[k]);
      }
      __builtin_amdgcn_wave_barrier();
    }

    // combine the two 32-lane halves
#pragma unroll
    for (int k = 0; k < 8; ++k) acc[k] += __shfl_xor(acc[k], 32);

    if (lane < 32) {
      float v[8];
#pragma unroll
      for (int k = 0; k < 8; ++k) v[k] = acc[k] + bv[k];
      if (hres) {
        short8 r8 = *(const short8*)(hres + (size_t)n * 256 + l32 * 8);
#pragma unroll
        for (int k = 0; k < 8; ++k) v[k] += b2f((unsigned short)r8[k]);
      }
#pragma unroll
      for (int k = 0; k < 8; ++k) v[k] = eluf(v[k]);
      if (mode == 0) {
        short8 o;
#pragma unroll
        for (int k = 0; k < 8; ++k) o[k] = (short)f2b(v[k]);
        *(short8*)(hout + (size_t)n * 256 + l32 * 8) = o;
      } else {
#pragma unroll
        for (int k = 0; k < 8; ++k) t[k] += v[k];
      }
    }
  }

  if (mode == 1) {
    if (lane < 32) {
#pragma unroll
      for (int k = 0; k < 8; ++k) psum[wave][l32 * 8 + k] = t[k];
    }
    __syncthreads();
    int tt = threadIdx.x;
    partial[(size_t)blockIdx.x * 256 + tt] =
        psum[0][tt] + psum[1][tt] + psum[2][tt] + psum[3][tt];
  }
}

// ---------------- reduce partial column sums -> s[256]
__global__ __launch_bounds__(256) void reduce_partials(const float* __restrict__ partial,
                                                       float* __restrict__ s, int rows) {
  int t = threadIdx.x;
  float acc = 0.f;
  for (int r = blockIdx.x; r < rows; r += gridDim.x) acc += partial[(size_t)r * 256 + t];
  atomicAdd(&s[t], acc);
}

// ---------------- out[c] = (s/N) @ Wl + bl
__global__ __launch_bounds__(128) void final_linear(const float* __restrict__ s,
                                                    const float* __restrict__ Wl,
                                                    const float* __restrict__ bl,
                                                    float* __restrict__ out, float invN) {
  int c = threadIdx.x;
  float acc = 0.f;
  for (int k = 0; k < 256; ++k) acc = fmaf(s[k], Wl[k * 128 + c], acc);
  out[c] = acc * invN + bl[c];
}

extern "C" void kernel_launch(void* const* d_in, const int* in_sizes, int n_in, void* d_out,
                              int out_size, void* d_ws, size_t ws_size, hipStream_t stream) {
  const float* x  = (const float*)d_in[0];
  const int* src  = (const int*)d_in[1];
  const int* dst  = (const int*)d_in[2];
  const float* W1 = (const float*)d_in[3];
  const float* al1 = (const float*)d_in[4];
  const float* ar1 = (const float*)d_in[5];
  const float* b1 = (const float*)d_in[6];
  const float* W2 = (const float*)d_in[7];
  const float* al2 = (const float*)d_in[8];
  const float* ar2 = (const float*)d_in[9];
  const float* b2 = (const float*)d_in[10];
  const float* Wl = (const float*)d_in[11];
  const float* bl = (const float*)d_in[12];
  float* out = (float*)d_out;

  const int N = in_sizes[0] / 128;  // 50000
  const int E = in_sizes[1];        // 800000
  const int AGG_BLOCKS = 2048;

  // ---- workspace carve
  char* w = (char*)d_ws;
  unsigned short* xb    = (unsigned short*)w; w += (size_t)N * 128 * 2;
  unsigned short* featb = (unsigned short*)w; w += (size_t)N * 256 * 2;
  unsigned short* h1b   = (unsigned short*)w; w += (size_t)N * 256 * 2;
  unsigned short* W1t   = (unsigned short*)w; w += (size_t)256 * 128 * 2;
  unsigned short* W2t   = (unsigned short*)w; w += (size_t)256 * 256 * 2;
  float* el = (float*)w;        w += (size_t)N * 8 * 4;
  float* er = (float*)w;        w += (size_t)N * 8 * 4;
  int* offs = (int*)w;          w += (size_t)(N + 64) * 4;
  int* deg = (int*)w;           w += (size_t)N * 4;
  int* cursor = (int*)w;        w += (size_t)(N + 64) * 4;
  int* csrc = (int*)w;          w += (size_t)E * 4;
  int* bsums = (int*)w;         w += 256 * 4;
  float* partial = (float*)w;   w += (size_t)AGG_BLOCKS * 256 * 4;
  float* svec = (float*)w;      w += 256 * 4;

  const int nb = (N + 255) / 256;
  const int eb = (E + 255) / 256;
  const int gmb = (N + BM - 1) / BM;
  const int nodeb = (N + 3) / 4;

  // ---- CSR build (dst-indexed)
  hipMemsetAsync(deg, 0, (size_t)N * 4, stream);
  hipMemsetAsync(svec, 0, 256 * 4, stream);
  deg_count<<<eb, 256, 0, stream>>>(dst, deg, E);
  scan1<<<nb, 256, 0, stream>>>(deg, offs, bsums, N);
  scan2<<<1, 256, 0, stream>>>(bsums, nb);
  scan3<<<nb, 256, 0, stream>>>(offs, bsums, cursor, N);
  scatter_edges<<<eb, 256, 0, stream>>>(src, dst, cursor, csrc, E);

  // ---- casts
  cast_bf16_vec<<<(N * 128 / 4 + 255) / 256, 256, 0, stream>>>(x, xb, N * 128 / 4);
  cast_w_both<<<((128 + 256) * 256 + 255) / 256, 256, 0, stream>>>(W1, W1t, W2, W2t);

  // ---- layer 1
  gemm_bf16<<<dim3(gmb, 4), 256, 0, stream>>>(xb, W1t, featb, N, 128);
  compute_elr<<<nodeb, 256, 0, stream>>>(featb, al1, ar1, el, er, N);
  gat_agg<<<AGG_BLOCKS, 256, 0, stream>>>(offs, csrc, featb, el, er, b1, nullptr, h1b, nullptr, N, 0);

  // ---- layer 2
  gemm_bf16<<<dim3(gmb, 4), 256, 0, stream>>>(h1b, W2t, featb, N, 256);
  compute_elr<<<nodeb, 256, 0, stream>>>(featb, al2, ar2, el, er, N);
  gat_agg<<<AGG_BLOCKS, 256, 0, stream>>>(offs, csrc, featb, el, er, b2, h1b, nullptr, partial, N, 1);

  // ---- mean over nodes, then final linear
  reduce_partials<<<64, 256, 0, stream>>>(partial, svec, AGG_BLOCKS);
  final_linear<<<1, 128, 0, stream>>>(svec, Wl, bl, out, 1.0f / (float)N);
}

// Round 4
// 448.072 us; speedup vs baseline: 1.0724x; 1.0724x over previous
//
#include <hip/hip_runtime.h>
#include <math.h>

#define NEG_SLOPE 0.2f

typedef __attribute__((ext_vector_type(8))) short short8;
typedef __attribute__((ext_vector_type(4))) float f32x4;
typedef __attribute__((ext_vector_type(16))) float f32x16;

__device__ __forceinline__ float lrelu(float x) { return x > 0.f ? x : NEG_SLOPE * x; }
__device__ __forceinline__ float eluf(float x) { return x > 0.f ? x : expm1f(x); }
__device__ __forceinline__ unsigned short f2b(float f) {
  unsigned int u = __float_as_uint(f);
  u += 0x7FFFu + ((u >> 16) & 1u);  // RNE
  return (unsigned short)(u >> 16);
}
__device__ __forceinline__ float b2f(unsigned short h) {
  return __uint_as_float(((unsigned int)h) << 16);
}

// ---------------- weight casts: W1 [128][256], W2 [256][256] fp32 -> transposed bf16 [256][K]
__global__ __launch_bounds__(256) void cast_w_both(const float* __restrict__ W1,
                                                   unsigned short* __restrict__ W1t,
                                                   const float* __restrict__ W2,
                                                   unsigned short* __restrict__ W2t) {
  int id = blockIdx.x * 256 + threadIdx.x;
  if (id < 128 * 256) {
    int k = id >> 8, n = id & 255;
    W1t[(size_t)n * 128 + k] = f2b(W1[id]);
  } else {
    int j = id - 128 * 256;
    if (j < 256 * 256) {
      int k = j >> 8, n = j & 255;
      W2t[(size_t)n * 256 + k] = f2b(W2[j]);
    }
  }
}

// ---------------- GEMM v2: C[M][256] = A[M][K] @ B (Bt[256][K] transposed bf16).
// BM=64 x BN=256 (full width, A fetched once), BK=32, 4 waves 2x2, 32x32x16 MFMA.
#define GBM 64
#define GBK 32
#define GLDK 36
__global__ __launch_bounds__(256) void gemm_bf16_v2(const void* __restrict__ Araw, int a_fp32,
                                                    const unsigned short* __restrict__ Bt,
                                                    unsigned short* __restrict__ C, int M, int K) {
  __shared__ unsigned short As[GBM][GLDK];
  __shared__ unsigned short Bs[256][GLDK];
  const int tid = threadIdx.x;
  const int wave = tid >> 6, lane = tid & 63;
  const int wm = wave >> 1, wn = wave & 1;
  const int l32 = lane & 31, lhalf = lane >> 5;
  const int row0 = blockIdx.x * GBM;

  f32x16 acc[4] = {};

  const int ar = tid >> 2;            // A staging: row 0..63
  const int ac = (tid & 3) * 8;       // k-chunk
  const bool arow_ok = (row0 + ar) < M;

  for (int kk = 0; kk < K; kk += GBK) {
    // stage A (64x32)
    short8 av = {};
    if (arow_ok) {
      if (a_fp32) {
        const float* p = (const float*)Araw + (size_t)(row0 + ar) * K + kk + ac;
        float4 lo = *(const float4*)p;
        float4 hi = *(const float4*)(p + 4);
        av[0] = (short)f2b(lo.x); av[1] = (short)f2b(lo.y);
        av[2] = (short)f2b(lo.z); av[3] = (short)f2b(lo.w);
        av[4] = (short)f2b(hi.x); av[5] = (short)f2b(hi.y);
        av[6] = (short)f2b(hi.z); av[7] = (short)f2b(hi.w);
      } else {
        av = *(const short8*)((const unsigned short*)Araw + (size_t)(row0 + ar) * K + kk + ac);
      }
    }
    *(short8*)&As[ar][ac] = av;
    // stage B (256x32): thread tid owns output-col tid, 4 chunks of 8
    {
      const unsigned short* bp = Bt + (size_t)tid * K + kk;
      short8 b0 = *(const short8*)(bp + 0);
      short8 b1 = *(const short8*)(bp + 8);
      short8 b2 = *(const short8*)(bp + 16);
      short8 b3 = *(const short8*)(bp + 24);
      *(short8*)&Bs[tid][0] = b0;
      *(short8*)&Bs[tid][8] = b1;
      *(short8*)&Bs[tid][16] = b2;
      *(short8*)&Bs[tid][24] = b3;
    }
    __syncthreads();
#pragma unroll
    for (int s = 0; s < 2; ++s) {
      short8 af = *(short8*)&As[wm * 32 + l32][s * 16 + lhalf * 8];
#pragma unroll
      for (int t = 0; t < 4; ++t) {
        short8 bf = *(short8*)&Bs[wn * 128 + t * 32 + l32][s * 16 + lhalf * 8];
        acc[t] = __builtin_amdgcn_mfma_f32_32x32x16_bf16(af, bf, acc[t], 0, 0, 0);
      }
    }
    __syncthreads();
  }

  // epilogue: col = lane&31 (+tile), row = (reg&3) + 8*(reg>>2) + 4*(lane>>5)
#pragma unroll
  for (int t = 0; t < 4; ++t) {
    int col = wn * 128 + t * 32 + l32;
#pragma unroll
    for (int reg = 0; reg < 16; ++reg) {
      int row = wm * 32 + (reg & 3) + 8 * (reg >> 2) + 4 * lhalf;
      int r = row0 + row;
      if (r < M) C[(size_t)r * 256 + col] = f2b(acc[t][reg]);
    }
  }
}

// ---------------- el/er from bf16 feat. One wave per node.
__global__ __launch_bounds__(256) void compute_elr(const unsigned short* __restrict__ feat,
                                                   const float* __restrict__ al,
                                                   const float* __restrict__ ar,
                                                   float* __restrict__ el,
                                                   float* __restrict__ er, int N) {
  int wave = threadIdx.x >> 6, lane = threadIdx.x & 63;
  int n = blockIdx.x * 4 + wave;
  if (n >= N) return;
  ushort4 fu = *(const ushort4*)(feat + (size_t)n * 256 + lane * 4);
  float4 a = *(const float4*)(al + lane * 4);
  float4 b = *(const float4*)(ar + lane * 4);
  float f0 = b2f(fu.x), f1 = b2f(fu.y), f2 = b2f(fu.z), f3 = b2f(fu.w);
  float sl = f0 * a.x + f1 * a.y + f2 * a.z + f3 * a.w;
  float sr = f0 * b.x + f1 * b.y + f2 * b.z + f3 * b.w;
#pragma unroll
  for (int d = 1; d < 8; d <<= 1) {
    sl += __shfl_xor(sl, d);
    sr += __shfl_xor(sr, d);
  }
  if ((lane & 7) == 0) {
    el[n * 8 + (lane >> 3)] = sl;
    er[n * 8 + (lane >> 3)] = sr;
  }
}

// ---------------- CSR build
__global__ void deg_count(const int* __restrict__ dst, int* __restrict__ deg, int E) {
  int i = blockIdx.x * blockDim.x + threadIdx.x;
  if (i < E) atomicAdd(&deg[dst[i]], 1);
}

__global__ __launch_bounds__(256) void scan1(const int* __restrict__ deg, int* __restrict__ offs,
                                             int* __restrict__ bsums, int n) {
  __shared__ int sh[256];
  int i = blockIdx.x * 256 + threadIdx.x;
  int v = (i < n) ? deg[i] : 0;
  sh[threadIdx.x] = v;
  __syncthreads();
  for (int d = 1; d < 256; d <<= 1) {
    int t = (threadIdx.x >= d) ? sh[threadIdx.x - d] : 0;
    __syncthreads();
    sh[threadIdx.x] += t;
    __syncthreads();
  }
  if (i < n) offs[i + 1] = sh[threadIdx.x];
  if (threadIdx.x == 255) bsums[blockIdx.x] = sh[255];
  if (i == 0) offs[0] = 0;
}

__global__ __launch_bounds__(256) void scan2(int* __restrict__ bsums, int nb) {
  __shared__ int sh[256];
  int t = threadIdx.x;
  int v = (t < nb) ? bsums[t] : 0;
  sh[t] = v;
  __syncthreads();
  for (int d = 1; d < 256; d <<= 1) {
    int tmp = (t >= d) ? sh[t - d] : 0;
    __syncthreads();
    sh[t] += tmp;
    __syncthreads();
  }
  if (t < nb) bsums[t] = (t == 0) ? 0 : sh[t - 1];
}

// also writes cursor = final offsets (replaces D2D copy)
__global__ __launch_bounds__(256) void scan3(int* __restrict__ offs, const int* __restrict__ bsums,
                                             int* __restrict__ cursor, int n) {
  int i = blockIdx.x * 256 + threadIdx.x;
  if (i < n) {
    int v = offs[i + 1] + bsums[blockIdx.x];
    offs[i + 1] = v;
    cursor[i + 1] = v;
  }
  if (i == 0) cursor[0] = 0;
}

__global__ void scatter_edges(const int* __restrict__ src, const int* __restrict__ dst,
                              int* __restrict__ cursor, int* __restrict__ csrc, int E) {
  int i = blockIdx.x * blockDim.x + threadIdx.x;
  if (i < E) {
    int d = dst[i];
    int pos = atomicAdd(&cursor[d], 1);
    csrc[pos] = src[i];
  }
}

// ---------------- GAT aggregation: one wave per dst node (R1 structure).
__global__ __launch_bounds__(256) void gat_agg(const int* __restrict__ offs,
                                               const int* __restrict__ csrc,
                                               const unsigned short* __restrict__ feat,
                                               const float* __restrict__ el,
                                               const float* __restrict__ er,
                                               const float* __restrict__ bias,
                                               const unsigned short* __restrict__ hres,
                                               unsigned short* __restrict__ hout,
                                               float* __restrict__ partial, int N, int mode) {
  __shared__ float psum[4][256];
  const int wave = threadIdx.x >> 6;
  const int lane = threadIdx.x & 63;
  const int hh = lane & 7;    // head for softmax phases
  const int myh = lane >> 3;  // head owning my features
  float4 bvec = *(const float4*)(bias + lane * 4);
  float t0 = 0.f, t1 = 0.f, t2 = 0.f, t3 = 0.f;

  for (int n = blockIdx.x * 4 + wave; n < N; n += gridDim.x * 4) {
    const int o0 = offs[n];
    const int deg = offs[n + 1] - o0;
    const float er_h = er[n * 8 + hh];

    // phase 1: online softmax stats (8 edge-slots x 8 heads)
    float m = -1e30f, ssum = 0.f;
    for (int base = 0; base < deg; base += 8) {
      int idx = base + (lane >> 3);
      if (idx < deg) {
        int s = csrc[o0 + idx];
        float e = lrelu(el[s * 8 + hh] + er_h);
        float mn = fmaxf(m, e);
        ssum = ssum * __expf(m - mn) + __expf(e - mn);
        m = mn;
      }
    }
#pragma unroll
    for (int d = 8; d < 64; d <<= 1) {
      float mo = __shfl_xor(m, d);
      float so = __shfl_xor(ssum, d);
      float mn = fmaxf(m, mo);
      ssum = ssum * __expf(m - mn) + so * __expf(mo - mn);
      m = mn;
    }
    float inv_denom = (ssum > 0.f) ? 1.f / ssum : 0.f;

    // phase 2: weighted gather-accumulate (bf16 feat, 8B/lane/edge)
    float a0 = 0.f, a1 = 0.f, a2 = 0.f, a3 = 0.f;
    for (int base = 0; base < deg; base += 64) {
      int cnt = min(64, deg - base);
      int sreg = (base + lane < deg) ? csrc[o0 + base + lane] : 0;
      for (int j = 0; j < cnt; ++j) {
        int s = __shfl(sreg, j);
        float e = lrelu(el[s * 8 + hh] + er_h);
        float alpha = __expf(e - m) * inv_denom;
        float am = __shfl(alpha, myh);
        ushort4 fu = *(const ushort4*)(feat + (size_t)s * 256 + lane * 4);
        a0 = fmaf(am, b2f(fu.x), a0);
        a1 = fmaf(am, b2f(fu.y), a1);
        a2 = fmaf(am, b2f(fu.z), a2);
        a3 = fmaf(am, b2f(fu.w), a3);
      }
    }

    // epilogue
    float v0 = a0 + bvec.x, v1 = a1 + bvec.y, v2 = a2 + bvec.z, v3 = a3 + bvec.w;
    if (hres) {
      ushort4 r4 = *(const ushort4*)(hres + (size_t)n * 256 + lane * 4);
      v0 += b2f(r4.x); v1 += b2f(r4.y); v2 += b2f(r4.z); v3 += b2f(r4.w);
    }
    v0 = eluf(v0); v1 = eluf(v1); v2 = eluf(v2); v3 = eluf(v3);
    if (mode == 0) {
      ushort4 o;
      o.x = f2b(v0); o.y = f2b(v1); o.z = f2b(v2); o.w = f2b(v3);
      *(ushort4*)(hout + (size_t)n * 256 + lane * 4) = o;
    } else {
      t0 += v0; t1 += v1; t2 += v2; t3 += v3;
    }
  }

  if (mode == 1) {
    psum[wave][lane * 4 + 0] = t0;
    psum[wave][lane * 4 + 1] = t1;
    psum[wave][lane * 4 + 2] = t2;
    psum[wave][lane * 4 + 3] = t3;
    __syncthreads();
    int t = threadIdx.x;
    partial[(size_t)blockIdx.x * 256 + t] = psum[0][t] + psum[1][t] + psum[2][t] + psum[3][t];
  }
}

// ---------------- reduce partial column sums -> s[256]
__global__ __launch_bounds__(256) void reduce_partials(const float* __restrict__ partial,
                                                       float* __restrict__ s, int rows) {
  int t = threadIdx.x;
  float acc = 0.f;
  for (int r = blockIdx.x; r < rows; r += gridDim.x) acc += partial[(size_t)r * 256 + t];
  atomicAdd(&s[t], acc);
}

// ---------------- out[c] = (s/N) @ Wl + bl
__global__ __launch_bounds__(128) void final_linear(const float* __restrict__ s,
                                                    const float* __restrict__ Wl,
                                                    const float* __restrict__ bl,
                                                    float* __restrict__ out, float invN) {
  int c = threadIdx.x;
  float acc = 0.f;
  for (int k = 0; k < 256; ++k) acc = fmaf(s[k], Wl[k * 128 + c], acc);
  out[c] = acc * invN + bl[c];
}

extern "C" void kernel_launch(void* const* d_in, const int* in_sizes, int n_in, void* d_out,
                              int out_size, void* d_ws, size_t ws_size, hipStream_t stream) {
  const float* x  = (const float*)d_in[0];
  const int* src  = (const int*)d_in[1];
  const int* dst  = (const int*)d_in[2];
  const float* W1 = (const float*)d_in[3];
  const float* al1 = (const float*)d_in[4];
  const float* ar1 = (const float*)d_in[5];
  const float* b1 = (const float*)d_in[6];
  const float* W2 = (const float*)d_in[7];
  const float* al2 = (const float*)d_in[8];
  const float* ar2 = (const float*)d_in[9];
  const float* b2 = (const float*)d_in[10];
  const float* Wl = (const float*)d_in[11];
  const float* bl = (const float*)d_in[12];
  float* out = (float*)d_out;

  const int N = in_sizes[0] / 128;  // 50000
  const int E = in_sizes[1];        // 800000
  const int AGG_BLOCKS = 2048;

  // ---- workspace carve
  char* w = (char*)d_ws;
  unsigned short* featb = (unsigned short*)w; w += (size_t)N * 256 * 2;
  unsigned short* h1b   = (unsigned short*)w; w += (size_t)N * 256 * 2;
  unsigned short* W1t   = (unsigned short*)w; w += (size_t)256 * 128 * 2;
  unsigned short* W2t   = (unsigned short*)w; w += (size_t)256 * 256 * 2;
  float* el = (float*)w;        w += (size_t)N * 8 * 4;
  float* er = (float*)w;        w += (size_t)N * 8 * 4;
  int* offs = (int*)w;          w += (size_t)(N + 64) * 4;
  int* deg = (int*)w;           w += (size_t)N * 4;
  int* cursor = (int*)w;        w += (size_t)(N + 64) * 4;
  int* csrc = (int*)w;          w += (size_t)E * 4;
  int* bsums = (int*)w;         w += 256 * 4;
  float* partial = (float*)w;   w += (size_t)AGG_BLOCKS * 256 * 4;
  float* svec = (float*)w;      w += 256 * 4;

  const int nb = (N + 255) / 256;
  const int eb = (E + 255) / 256;
  const int gmb = (N + GBM - 1) / GBM;  // 782
  const int nodeb = (N + 3) / 4;

  // ---- CSR build (dst-indexed)
  hipMemsetAsync(deg, 0, (size_t)N * 4, stream);
  hipMemsetAsync(svec, 0, 256 * 4, stream);
  deg_count<<<eb, 256, 0, stream>>>(dst, deg, E);
  scan1<<<nb, 256, 0, stream>>>(deg, offs, bsums, N);
  scan2<<<1, 256, 0, stream>>>(bsums, nb);
  scan3<<<nb, 256, 0, stream>>>(offs, bsums, cursor, N);
  scatter_edges<<<eb, 256, 0, stream>>>(src, dst, cursor, csrc, E);

  // ---- weight casts
  cast_w_both<<<((128 + 256) * 256 + 255) / 256, 256, 0, stream>>>(W1, W1t, W2, W2t);

  // ---- layer 1 (A = x fp32, cast folded into GEMM staging)
  gemm_bf16_v2<<<gmb, 256, 0, stream>>>(x, 1, W1t, featb, N, 128);
  compute_elr<<<nodeb, 256, 0, stream>>>(featb, al1, ar1, el, er, N);
  gat_agg<<<AGG_BLOCKS, 256, 0, stream>>>(offs, csrc, featb, el, er, b1, nullptr, h1b, nullptr, N, 0);

  // ---- layer 2
  gemm_bf16_v2<<<gmb, 256, 0, stream>>>(h1b, 0, W2t, featb, N, 256);
  compute_elr<<<nodeb, 256, 0, stream>>>(featb, al2, ar2, el, er, N);
  gat_agg<<<AGG_BLOCKS, 256, 0, stream>>>(offs, csrc, featb, el, er, b2, h1b, nullptr, partial, N, 1);

  // ---- mean over nodes, then final linear
  reduce_partials<<<64, 256, 0, stream>>>(partial, svec, AGG_BLOCKS);
  final_linear<<<1, 128, 0, stream>>>(svec, Wl, bl, out, 1.0f / (float)N);
}

// Round 5
// 446.961 us; speedup vs baseline: 1.0751x; 1.0025x over previous
//
#include <hip/hip_runtime.h>
#include <math.h>

#define NEG_SLOPE 0.2f

typedef __attribute__((ext_vector_type(8))) short short8;
typedef __attribute__((ext_vector_type(4))) float f32x4;
typedef __attribute__((ext_vector_type(16))) float f32x16;

__device__ __forceinline__ float lrelu(float x) { return x > 0.f ? x : NEG_SLOPE * x; }
__device__ __forceinline__ float eluf(float x) { return x > 0.f ? x : expm1f(x); }
__device__ __forceinline__ unsigned short f2b(float f) {
  unsigned int u = __float_as_uint(f);
  u += 0x7FFFu + ((u >> 16) & 1u);  // RNE
  return (unsigned short)(u >> 16);
}
__device__ __forceinline__ float b2f(unsigned short h) {
  return __uint_as_float(((unsigned int)h) << 16);
}

// ---------------- weights: build extended Bt for both layers.
// B1t[288][128]: rows 0..255 = W1^T bf16; rows 256..263 = P_el (W1 slice . al1),
// rows 264..271 = P_er, rows 272..287 = 0.   B2t[288][256] likewise.
__global__ __launch_bounds__(256) void cast_w_both(const float* __restrict__ W1,
                                                   unsigned short* __restrict__ B1t,
                                                   const float* __restrict__ W2,
                                                   unsigned short* __restrict__ B2t,
                                                   const float* __restrict__ al1,
                                                   const float* __restrict__ ar1,
                                                   const float* __restrict__ al2,
                                                   const float* __restrict__ ar2) {
  int id = blockIdx.x * 256 + threadIdx.x;
  if (id < 128 * 256) {                      // W1 transpose-cast
    int k = id >> 8, n = id & 255;
    B1t[(size_t)n * 128 + k] = f2b(W1[id]);
    return;
  }
  id -= 128 * 256;
  if (id < 256 * 256) {                      // W2 transpose-cast
    int k = id >> 8, n = id & 255;
    B2t[(size_t)n * 256 + k] = f2b(W2[id]);
    return;
  }
  id -= 256 * 256;
  if (id < 128 * 16) {                       // P1: k in 0..127, h2 in 0..15
    int k = id >> 4, h2 = id & 15;
    int h = h2 & 7;
    const float* av = (h2 < 8) ? al1 : ar1;
    float acc = 0.f;
    for (int d = 0; d < 32; ++d) acc = fmaf(W1[(size_t)k * 256 + h * 32 + d], av[h * 32 + d], acc);
    B1t[(size_t)(256 + h2) * 128 + k] = f2b(acc);
    return;
  }
  id -= 128 * 16;
  if (id < 256 * 16) {                       // P2
    int k = id >> 4, h2 = id & 15;
    int h = h2 & 7;
    const float* av = (h2 < 8) ? al2 : ar2;
    float acc = 0.f;
    for (int d = 0; d < 32; ++d) acc = fmaf(W2[(size_t)k * 256 + h * 32 + d], av[h * 32 + d], acc);
    B2t[(size_t)(256 + h2) * 256 + k] = f2b(acc);
    return;
  }
  id -= 256 * 16;
  if (id < 16 * 128) {                       // zero-pad B1t rows 272..287
    int k = id & 127, rr = 272 + (id >> 7);
    B1t[(size_t)rr * 128 + k] = 0;
    return;
  }
  id -= 16 * 128;
  if (id < 16 * 256) {                       // zero-pad B2t rows 272..287
    int k = id & 255, rr = 272 + (id >> 8);
    B2t[(size_t)rr * 256 + k] = 0;
  }
}

// ---------------- GEMM: C[M][256] = A[M][K] @ B  (Bt[288][K] extended-transposed bf16).
// BM=64 x BN=256(+32 el/er cols), BK=32, 4 waves 2x2, 32x32x16 MFMA.
// Epilogue also writes el/er fp32 from the extra tile.
#define GBM 64
#define GBK 32
#define GLDK 36
__global__ __launch_bounds__(256) void gemm_bf16_v3(const void* __restrict__ Araw, int a_fp32,
                                                    const unsigned short* __restrict__ Bt,
                                                    unsigned short* __restrict__ C,
                                                    float* __restrict__ el, float* __restrict__ er,
                                                    int M, int K) {
  __shared__ unsigned short As[GBM][GLDK];
  __shared__ unsigned short Bs[288][GLDK];
  const int tid = threadIdx.x;
  const int wave = tid >> 6, lane = tid & 63;
  const int wm = wave >> 1, wn = wave & 1;
  const int l32 = lane & 31, lhalf = lane >> 5;
  const int row0 = blockIdx.x * GBM;

  f32x16 acc[4] = {};
  f32x16 acc4 = {};

  const int ar = tid >> 2;       // A staging: row 0..63
  const int ac = (tid & 3) * 8;  // k-chunk
  const bool arow_ok = (row0 + ar) < M;

  for (int kk = 0; kk < K; kk += GBK) {
    // stage A (64x32)
    short8 av = {};
    if (arow_ok) {
      if (a_fp32) {
        const float* p = (const float*)Araw + (size_t)(row0 + ar) * K + kk + ac;
        float4 lo = *(const float4*)p;
        float4 hi = *(const float4*)(p + 4);
        av[0] = (short)f2b(lo.x); av[1] = (short)f2b(lo.y);
        av[2] = (short)f2b(lo.z); av[3] = (short)f2b(lo.w);
        av[4] = (short)f2b(hi.x); av[5] = (short)f2b(hi.y);
        av[6] = (short)f2b(hi.z); av[7] = (short)f2b(hi.w);
      } else {
        av = *(const short8*)((const unsigned short*)Araw + (size_t)(row0 + ar) * K + kk + ac);
      }
    }
    *(short8*)&As[ar][ac] = av;
    // stage B rows 0..255 (thread -> row) + rows 256..287 (threads 0..31)
    {
      const unsigned short* bp = Bt + (size_t)tid * K + kk;
      short8 b0 = *(const short8*)(bp + 0);
      short8 b1 = *(const short8*)(bp + 8);
      short8 b2 = *(const short8*)(bp + 16);
      short8 b3 = *(const short8*)(bp + 24);
      *(short8*)&Bs[tid][0] = b0;
      *(short8*)&Bs[tid][8] = b1;
      *(short8*)&Bs[tid][16] = b2;
      *(short8*)&Bs[tid][24] = b3;
    }
    if (tid < 32) {
      const unsigned short* bp = Bt + (size_t)(256 + tid) * K + kk;
      short8 b0 = *(const short8*)(bp + 0);
      short8 b1 = *(const short8*)(bp + 8);
      short8 b2 = *(const short8*)(bp + 16);
      short8 b3 = *(const short8*)(bp + 24);
      *(short8*)&Bs[256 + tid][0] = b0;
      *(short8*)&Bs[256 + tid][8] = b1;
      *(short8*)&Bs[256 + tid][16] = b2;
      *(short8*)&Bs[256 + tid][24] = b3;
    }
    __syncthreads();
#pragma unroll
    for (int s = 0; s < 2; ++s) {
      short8 af = *(short8*)&As[wm * 32 + l32][s * 16 + lhalf * 8];
#pragma unroll
      for (int t = 0; t < 4; ++t) {
        short8 bf = *(short8*)&Bs[wn * 128 + t * 32 + l32][s * 16 + lhalf * 8];
        acc[t] = __builtin_amdgcn_mfma_f32_32x32x16_bf16(af, bf, acc[t], 0, 0, 0);
      }
      if (wn == 1) {
        short8 bf = *(short8*)&Bs[256 + l32][s * 16 + lhalf * 8];
        acc4 = __builtin_amdgcn_mfma_f32_32x32x16_bf16(af, bf, acc4, 0, 0, 0);
      }
    }
    __syncthreads();
  }

  // epilogue: col = lane&31 (+tile), row = (reg&3) + 8*(reg>>2) + 4*(lane>>5)
#pragma unroll
  for (int t = 0; t < 4; ++t) {
    int col = wn * 128 + t * 32 + l32;
#pragma unroll
    for (int reg = 0; reg < 16; ++reg) {
      int row = wm * 32 + (reg & 3) + 8 * (reg >> 2) + 4 * lhalf;
      int r = row0 + row;
      if (r < M) C[(size_t)r * 256 + col] = f2b(acc[t][reg]);
    }
  }
  if (wn == 1 && l32 < 16) {
#pragma unroll
    for (int reg = 0; reg < 16; ++reg) {
      int row = wm * 32 + (reg & 3) + 8 * (reg >> 2) + 4 * lhalf;
      int r = row0 + row;
      if (r < M) {
        if (l32 < 8) el[r * 8 + l32] = acc4[reg];
        else er[r * 8 + (l32 - 8)] = acc4[reg];
      }
    }
  }
}

// ---------------- CSR build
__global__ void deg_count(const int* __restrict__ dst, int* __restrict__ deg, int E) {
  int i = blockIdx.x * blockDim.x + threadIdx.x;
  if (i < E) atomicAdd(&deg[dst[i]], 1);
}

__global__ __launch_bounds__(256) void scan1(const int* __restrict__ deg, int* __restrict__ offs,
                                             int* __restrict__ bsums, int n) {
  __shared__ int sh[256];
  int i = blockIdx.x * 256 + threadIdx.x;
  int v = (i < n) ? deg[i] : 0;
  sh[threadIdx.x] = v;
  __syncthreads();
  for (int d = 1; d < 256; d <<= 1) {
    int t = (threadIdx.x >= d) ? sh[threadIdx.x - d] : 0;
    __syncthreads();
    sh[threadIdx.x] += t;
    __syncthreads();
  }
  if (i < n) offs[i + 1] = sh[threadIdx.x];
  if (threadIdx.x == 255) bsums[blockIdx.x] = sh[255];
  if (i == 0) offs[0] = 0;
}

__global__ __launch_bounds__(256) void scan2(int* __restrict__ bsums, int nb) {
  __shared__ int sh[256];
  int t = threadIdx.x;
  int v = (t < nb) ? bsums[t] : 0;
  sh[t] = v;
  __syncthreads();
  for (int d = 1; d < 256; d <<= 1) {
    int tmp = (t >= d) ? sh[t - d] : 0;
    __syncthreads();
    sh[t] += tmp;
    __syncthreads();
  }
  if (t < nb) bsums[t] = (t == 0) ? 0 : sh[t - 1];
}

// also writes cursor = final offsets
__global__ __launch_bounds__(256) void scan3(int* __restrict__ offs, const int* __restrict__ bsums,
                                             int* __restrict__ cursor, int n) {
  int i = blockIdx.x * 256 + threadIdx.x;
  if (i < n) {
    int v = offs[i + 1] + bsums[blockIdx.x];
    offs[i + 1] = v;
    cursor[i + 1] = v;
  }
  if (i == 0) cursor[0] = 0;
}

__global__ void scatter_edges(const int* __restrict__ src, const int* __restrict__ dst,
                              int* __restrict__ cursor, int* __restrict__ csrc, int E) {
  int i = blockIdx.x * blockDim.x + threadIdx.x;
  if (i < E) {
    int d = dst[i];
    int pos = atomicAdd(&cursor[d], 1);
    csrc[pos] = src[i];
  }
}

// ---------------- GAT aggregation: one wave per dst node, shuffle-free phase 2,
// 2 edges per iteration (32 lanes x 16B each).
__global__ __launch_bounds__(256) void gat_agg(const int* __restrict__ offs,
                                               const int* __restrict__ csrc,
                                               const unsigned short* __restrict__ feat,
                                               const float* __restrict__ el,
                                               const float* __restrict__ er,
                                               const float* __restrict__ bias,
                                               const unsigned short* __restrict__ hres,
                                               unsigned short* __restrict__ hout,
                                               float* __restrict__ partial, int N, int mode) {
  __shared__ float psum[4][256];
  const int wave = threadIdx.x >> 6;
  const int lane = threadIdx.x & 63;
  const int hh = lane & 7;      // head for softmax stats (8 slots x 8 heads)
  const int slot = lane >> 3;
  const int epair = lane >> 5;  // phase 2: which edge of the pair
  const int l32 = lane & 31;    // phase 2: feature block l32*8 .. +7
  const int fh = l32 >> 2;      // phase 2: head of my feature block

  // bias for my 8 features (lanes 0..31 use it)
  float bv[8];
  {
    float4 blo = *(const float4*)(bias + l32 * 8);
    float4 bhi = *(const float4*)(bias + l32 * 8 + 4);
    bv[0] = blo.x; bv[1] = blo.y; bv[2] = blo.z; bv[3] = blo.w;
    bv[4] = bhi.x; bv[5] = bhi.y; bv[6] = bhi.z; bv[7] = bhi.w;
  }
  float t[8] = {};

  for (int n = blockIdx.x * 4 + wave; n < N; n += gridDim.x * 4) {
    const int o0 = offs[n];
    const int deg = offs[n + 1] - o0;
    const float er_h = er[n * 8 + hh];

    // ---- phase 1: online softmax stats
    float m = -1e30f, ssum = 0.f;
    for (int base = 0; base < deg; base += 8) {
      int idx = base + slot;
      if (idx < deg) {
        int s = csrc[o0 + idx];
        float e = lrelu(el[s * 8 + hh] + er_h);
        float mn = fmaxf(m, e);
        ssum = ssum * __expf(m - mn) + __expf(e - mn);
        m = mn;
      }
    }
#pragma unroll
    for (int d = 8; d < 64; d <<= 1) {
      float mo = __shfl_xor(m, d);
      float so = __shfl_xor(ssum, d);
      float mn = fmaxf(m, mo);
      ssum = ssum * __expf(m - mn) + so * __expf(mo - mn);
      m = mn;
    }
    float inv_denom = (ssum > 0.f) ? 1.f / ssum : 0.f;

    // redistribute per-head stats to phase-2 layout (once per node)
    const float m_f = __shfl(m, fh);
    const float inv_f = __shfl(inv_denom, fh);
    const float er_f = __shfl(er_h, fh);

    // ---- phase 2: 2 edges/iter, no cross-lane ops
    float acc[8] = {};
    for (int j = 0; j < deg; j += 2) {
      int eidx = j + epair;
      int s = 0;
      float am = 0.f;
      if (eidx < deg) {
        s = csrc[o0 + eidx];
        float e = lrelu(el[s * 8 + fh] + er_f);
        am = __expf(e - m_f) * inv_f;
      }
      short8 f = *(const short8*)(feat + (size_t)s * 256 + l32 * 8);
#pragma unroll
      for (int k = 0; k < 8; ++k)
        acc[k] = fmaf(am, b2f((unsigned short)f[k]), acc[k]);
    }

    // combine the two 32-lane halves
#pragma unroll
    for (int k = 0; k < 8; ++k) acc[k] += __shfl_xor(acc[k], 32);

    if (lane < 32) {
      float v[8];
#pragma unroll
      for (int k = 0; k < 8; ++k) v[k] = acc[k] + bv[k];
      if (hres) {
        short8 r8 = *(const short8*)(hres + (size_t)n * 256 + l32 * 8);
#pragma unroll
        for (int k = 0; k < 8; ++k) v[k] += b2f((unsigned short)r8[k]);
      }
#pragma unroll
      for (int k = 0; k < 8; ++k) v[k] = eluf(v[k]);
      if (mode == 0) {
        short8 o;
#pragma unroll
        for (int k = 0; k < 8; ++k) o[k] = (short)f2b(v[k]);
        *(short8*)(hout + (size_t)n * 256 + l32 * 8) = o;
      } else {
#pragma unroll
        for (int k = 0; k < 8; ++k) t[k] += v[k];
      }
    }
  }

  if (mode == 1) {
    if (lane < 32) {
#pragma unroll
      for (int k = 0; k < 8; ++k) psum[wave][l32 * 8 + k] = t[k];
    }
    __syncthreads();
    int tt = threadIdx.x;
    partial[(size_t)blockIdx.x * 256 + tt] =
        psum[0][tt] + psum[1][tt] + psum[2][tt] + psum[3][tt];
  }
}

// ---------------- reduce partial column sums -> s[256]
__global__ __launch_bounds__(256) void reduce_partials(const float* __restrict__ partial,
                                                       float* __restrict__ s, int rows) {
  int t = threadIdx.x;
  float acc = 0.f;
  for (int r = blockIdx.x; r < rows; r += gridDim.x) acc += partial[(size_t)r * 256 + t];
  atomicAdd(&s[t], acc);
}

// ---------------- out[c] = (s/N) @ Wl + bl
__global__ __launch_bounds__(128) void final_linear(const float* __restrict__ s,
                                                    const float* __restrict__ Wl,
                                                    const float* __restrict__ bl,
                                                    float* __restrict__ out, float invN) {
  int c = threadIdx.x;
  float acc = 0.f;
  for (int k = 0; k < 256; ++k) acc = fmaf(s[k], Wl[k * 128 + c], acc);
  out[c] = acc * invN + bl[c];
}

extern "C" void kernel_launch(void* const* d_in, const int* in_sizes, int n_in, void* d_out,
                              int out_size, void* d_ws, size_t ws_size, hipStream_t stream) {
  const float* x  = (const float*)d_in[0];
  const int* src  = (const int*)d_in[1];
  const int* dst  = (const int*)d_in[2];
  const float* W1 = (const float*)d_in[3];
  const float* al1 = (const float*)d_in[4];
  const float* ar1 = (const float*)d_in[5];
  const float* b1 = (const float*)d_in[6];
  const float* W2 = (const float*)d_in[7];
  const float* al2 = (const float*)d_in[8];
  const float* ar2 = (const float*)d_in[9];
  const float* b2 = (const float*)d_in[10];
  const float* Wl = (const float*)d_in[11];
  const float* bl = (const float*)d_in[12];
  float* out = (float*)d_out;

  const int N = in_sizes[0] / 128;  // 50000
  const int E = in_sizes[1];        // 800000
  const int AGG_BLOCKS = 2048;

  // ---- workspace carve (deg and svec adjacent -> one memset)
  char* w = (char*)d_ws;
  unsigned short* featb = (unsigned short*)w; w += (size_t)N * 256 * 2;
  unsigned short* h1b   = (unsigned short*)w; w += (size_t)N * 256 * 2;
  unsigned short* B1t   = (unsigned short*)w; w += (size_t)288 * 128 * 2;
  unsigned short* B2t   = (unsigned short*)w; w += (size_t)288 * 256 * 2;
  float* el = (float*)w;        w += (size_t)N * 8 * 4;
  float* er = (float*)w;        w += (size_t)N * 8 * 4;
  int* offs = (int*)w;          w += (size_t)(N + 64) * 4;
  int* deg = (int*)w;           w += (size_t)N * 4;
  float* svec = (float*)w;      w += 256 * 4;
  int* cursor = (int*)w;        w += (size_t)(N + 64) * 4;
  int* csrc = (int*)w;          w += (size_t)E * 4;
  int* bsums = (int*)w;         w += 256 * 4;
  float* partial = (float*)w;   w += (size_t)AGG_BLOCKS * 256 * 4;

  const int nb = (N + 255) / 256;
  const int eb = (E + 255) / 256;
  const int gmb = (N + GBM - 1) / GBM;  // 782

  // ---- CSR build (dst-indexed); deg+svec zeroed in one memset
  hipMemsetAsync(deg, 0, (size_t)(N + 256) * 4, stream);
  deg_count<<<eb, 256, 0, stream>>>(dst, deg, E);
  scan1<<<nb, 256, 0, stream>>>(deg, offs, bsums, N);
  scan2<<<1, 256, 0, stream>>>(bsums, nb);
  scan3<<<nb, 256, 0, stream>>>(offs, bsums, cursor, N);
  scatter_edges<<<eb, 256, 0, stream>>>(src, dst, cursor, csrc, E);

  // ---- weight casts + P (el/er projection) build: 110592 ids
  cast_w_both<<<432, 256, 0, stream>>>(W1, B1t, W2, B2t, al1, ar1, al2, ar2);

  // ---- layer 1 (A = x fp32, cast folded into staging; el/er from epilogue)
  gemm_bf16_v3<<<gmb, 256, 0, stream>>>(x, 1, B1t, featb, el, er, N, 128);
  gat_agg<<<AGG_BLOCKS, 256, 0, stream>>>(offs, csrc, featb, el, er, b1, nullptr, h1b, nullptr, N, 0);

  // ---- layer 2
  gemm_bf16_v3<<<gmb, 256, 0, stream>>>(h1b, 0, B2t, featb, el, er, N, 256);
  gat_agg<<<AGG_BLOCKS, 256, 0, stream>>>(offs, csrc, featb, el, er, b2, h1b, nullptr, partial, N, 1);

  // ---- mean over nodes, then final linear
  reduce_partials<<<64, 256, 0, stream>>>(partial, svec, AGG_BLOCKS);
  final_linear<<<1, 128, 0, stream>>>(svec, Wl, bl, out, 1.0f / (float)N);
}

// Round 6
// 427.203 us; speedup vs baseline: 1.1248x; 1.0462x over previous
//
#include <hip/hip_runtime.h>
#include <math.h>

#define NEG_SLOPE 0.2f

typedef __attribute__((ext_vector_type(8))) short short8;
typedef __attribute__((ext_vector_type(2))) float f32x2;
typedef __attribute__((ext_vector_type(4))) float f32x4;
typedef __attribute__((ext_vector_type(16))) float f32x16;

__device__ __forceinline__ float lrelu(float x) { return x > 0.f ? x : NEG_SLOPE * x; }
__device__ __forceinline__ float eluf(float x) { return x > 0.f ? x : expm1f(x); }
__device__ __forceinline__ unsigned short f2b(float f) {
  unsigned int u = __float_as_uint(f);
  u += 0x7FFFu + ((u >> 16) & 1u);  // RNE
  return (unsigned short)(u >> 16);
}
__device__ __forceinline__ float b2f(unsigned short h) {
  return __uint_as_float(((unsigned int)h) << 16);
}

// ---------------- weights: build extended Bt for both layers.
// B1t[288][128]: rows 0..255 = W1^T bf16; rows 256..263 = P_el (W1 . al1),
// rows 264..271 = P_er, rows 272..287 = 0.   B2t[288][256] likewise.
__global__ __launch_bounds__(256) void cast_w_both(const float* __restrict__ W1,
                                                   unsigned short* __restrict__ B1t,
                                                   const float* __restrict__ W2,
                                                   unsigned short* __restrict__ B2t,
                                                   const float* __restrict__ al1,
                                                   const float* __restrict__ ar1,
                                                   const float* __restrict__ al2,
                                                   const float* __restrict__ ar2) {
  int id = blockIdx.x * 256 + threadIdx.x;
  if (id < 128 * 256) {
    int k = id >> 8, n = id & 255;
    B1t[(size_t)n * 128 + k] = f2b(W1[id]);
    return;
  }
  id -= 128 * 256;
  if (id < 256 * 256) {
    int k = id >> 8, n = id & 255;
    B2t[(size_t)n * 256 + k] = f2b(W2[id]);
    return;
  }
  id -= 256 * 256;
  if (id < 128 * 16) {
    int k = id >> 4, h2 = id & 15;
    int h = h2 & 7;
    const float* av = (h2 < 8) ? al1 : ar1;
    float acc = 0.f;
    for (int d = 0; d < 32; ++d) acc = fmaf(W1[(size_t)k * 256 + h * 32 + d], av[h * 32 + d], acc);
    B1t[(size_t)(256 + h2) * 128 + k] = f2b(acc);
    return;
  }
  id -= 128 * 16;
  if (id < 256 * 16) {
    int k = id >> 4, h2 = id & 15;
    int h = h2 & 7;
    const float* av = (h2 < 8) ? al2 : ar2;
    float acc = 0.f;
    for (int d = 0; d < 32; ++d) acc = fmaf(W2[(size_t)k * 256 + h * 32 + d], av[h * 32 + d], acc);
    B2t[(size_t)(256 + h2) * 256 + k] = f2b(acc);
    return;
  }
  id -= 256 * 16;
  if (id < 16 * 128) {
    int k = id & 127, rr = 272 + (id >> 7);
    B1t[(size_t)rr * 128 + k] = 0;
    return;
  }
  id -= 16 * 128;
  if (id < 16 * 256) {
    int k = id & 255, rr = 272 + (id >> 8);
    B2t[(size_t)rr * 256 + k] = 0;
  }
}

// ---------------- GEMM: Cq[M][256] (fp8 e4m3) = A[M][K] @ B  (Bt[288][K] bf16).
// BM=64 x BN=256(+32 el/er cols), BK=32, 4 waves 2x2, 32x32x16 MFMA.
// Epilogue: C in fp8 (feeds gather only), el/er fp32 from extra tile.
#define GBM 64
#define GBK 32
#define GLDK 36
__global__ __launch_bounds__(256) void gemm_bf16_v4(const void* __restrict__ Araw, int a_fp32,
                                                    const unsigned short* __restrict__ Bt,
                                                    unsigned char* __restrict__ Cq,
                                                    float* __restrict__ el, float* __restrict__ er,
                                                    int M, int K) {
  __shared__ unsigned short As[GBM][GLDK];
  __shared__ unsigned short Bs[288][GLDK];
  const int tid = threadIdx.x;
  const int wave = tid >> 6, lane = tid & 63;
  const int wm = wave >> 1, wn = wave & 1;
  const int l32 = lane & 31, lhalf = lane >> 5;
  const int row0 = blockIdx.x * GBM;

  f32x16 acc[4] = {};
  f32x16 acc4 = {};

  const int ar = tid >> 2;
  const int ac = (tid & 3) * 8;
  const bool arow_ok = (row0 + ar) < M;

  for (int kk = 0; kk < K; kk += GBK) {
    short8 av = {};
    if (arow_ok) {
      if (a_fp32) {
        const float* p = (const float*)Araw + (size_t)(row0 + ar) * K + kk + ac;
        float4 lo = *(const float4*)p;
        float4 hi = *(const float4*)(p + 4);
        av[0] = (short)f2b(lo.x); av[1] = (short)f2b(lo.y);
        av[2] = (short)f2b(lo.z); av[3] = (short)f2b(lo.w);
        av[4] = (short)f2b(hi.x); av[5] = (short)f2b(hi.y);
        av[6] = (short)f2b(hi.z); av[7] = (short)f2b(hi.w);
      } else {
        av = *(const short8*)((const unsigned short*)Araw + (size_t)(row0 + ar) * K + kk + ac);
      }
    }
    *(short8*)&As[ar][ac] = av;
    {
      const unsigned short* bp = Bt + (size_t)tid * K + kk;
      short8 b0 = *(const short8*)(bp + 0);
      short8 b1 = *(const short8*)(bp + 8);
      short8 b2 = *(const short8*)(bp + 16);
      short8 b3 = *(const short8*)(bp + 24);
      *(short8*)&Bs[tid][0] = b0;
      *(short8*)&Bs[tid][8] = b1;
      *(short8*)&Bs[tid][16] = b2;
      *(short8*)&Bs[tid][24] = b3;
    }
    if (tid < 32) {
      const unsigned short* bp = Bt + (size_t)(256 + tid) * K + kk;
      short8 b0 = *(const short8*)(bp + 0);
      short8 b1 = *(const short8*)(bp + 8);
      short8 b2 = *(const short8*)(bp + 16);
      short8 b3 = *(const short8*)(bp + 24);
      *(short8*)&Bs[256 + tid][0] = b0;
      *(short8*)&Bs[256 + tid][8] = b1;
      *(short8*)&Bs[256 + tid][16] = b2;
      *(short8*)&Bs[256 + tid][24] = b3;
    }
    __syncthreads();
#pragma unroll
    for (int s = 0; s < 2; ++s) {
      short8 af = *(short8*)&As[wm * 32 + l32][s * 16 + lhalf * 8];
#pragma unroll
      for (int t = 0; t < 4; ++t) {
        short8 bf = *(short8*)&Bs[wn * 128 + t * 32 + l32][s * 16 + lhalf * 8];
        acc[t] = __builtin_amdgcn_mfma_f32_32x32x16_bf16(af, bf, acc[t], 0, 0, 0);
      }
      if (wn == 1) {
        short8 bf = *(short8*)&Bs[256 + l32][s * 16 + lhalf * 8];
        acc4 = __builtin_amdgcn_mfma_f32_32x32x16_bf16(af, bf, acc4, 0, 0, 0);
      }
    }
    __syncthreads();
  }

  // epilogue: col = lane&31 (+tile), row = (reg&3) + 8*(reg>>2) + 4*(lane>>5)
#pragma unroll
  for (int t = 0; t < 4; ++t) {
    int col = wn * 128 + t * 32 + l32;
#pragma unroll
    for (int reg = 0; reg < 16; ++reg) {
      int row = wm * 32 + (reg & 3) + 8 * (reg >> 2) + 4 * lhalf;
      int r = row0 + row;
      if (r < M) {
        int pk = __builtin_amdgcn_cvt_pk_fp8_f32(acc[t][reg], acc[t][reg], 0, false);
        Cq[(size_t)r * 256 + col] = (unsigned char)(pk & 0xFF);
      }
    }
  }
  if (wn == 1 && l32 < 16) {
#pragma unroll
    for (int reg = 0; reg < 16; ++reg) {
      int row = wm * 32 + (reg & 3) + 8 * (reg >> 2) + 4 * lhalf;
      int r = row0 + row;
      if (r < M) {
        if (l32 < 8) el[r * 8 + l32] = acc4[reg];
        else er[r * 8 + (l32 - 8)] = acc4[reg];
      }
    }
  }
}

// ---------------- CSR build
__global__ void deg_count(const int* __restrict__ dst, int* __restrict__ deg, int E) {
  int i = blockIdx.x * blockDim.x + threadIdx.x;
  if (i < E) atomicAdd(&deg[dst[i]], 1);
}

__global__ __launch_bounds__(256) void scan1(const int* __restrict__ deg, int* __restrict__ offs,
                                             int* __restrict__ bsums, int n) {
  __shared__ int sh[256];
  int i = blockIdx.x * 256 + threadIdx.x;
  int v = (i < n) ? deg[i] : 0;
  sh[threadIdx.x] = v;
  __syncthreads();
  for (int d = 1; d < 256; d <<= 1) {
    int t = (threadIdx.x >= d) ? sh[threadIdx.x - d] : 0;
    __syncthreads();
    sh[threadIdx.x] += t;
    __syncthreads();
  }
  if (i < n) offs[i + 1] = sh[threadIdx.x];
  if (threadIdx.x == 255) bsums[blockIdx.x] = sh[255];
  if (i == 0) offs[0] = 0;
}

__global__ __launch_bounds__(256) void scan2(int* __restrict__ bsums, int nb) {
  __shared__ int sh[256];
  int t = threadIdx.x;
  int v = (t < nb) ? bsums[t] : 0;
  sh[t] = v;
  __syncthreads();
  for (int d = 1; d < 256; d <<= 1) {
    int tmp = (t >= d) ? sh[t - d] : 0;
    __syncthreads();
    sh[t] += tmp;
    __syncthreads();
  }
  if (t < nb) bsums[t] = (t == 0) ? 0 : sh[t - 1];
}

__global__ __launch_bounds__(256) void scan3(int* __restrict__ offs, const int* __restrict__ bsums,
                                             int* __restrict__ cursor, int n) {
  int i = blockIdx.x * 256 + threadIdx.x;
  if (i < n) {
    int v = offs[i + 1] + bsums[blockIdx.x];
    offs[i + 1] = v;
    cursor[i + 1] = v;
  }
  if (i == 0) cursor[0] = 0;
}

__global__ void scatter_edges(const int* __restrict__ src, const int* __restrict__ dst,
                              int* __restrict__ cursor, int* __restrict__ csrc, int E) {
  int i = blockIdx.x * blockDim.x + threadIdx.x;
  if (i < E) {
    int d = dst[i];
    int pos = atomicAdd(&cursor[d], 1);
    csrc[pos] = src[i];
  }
}

// ---------------- GAT aggregation: one wave per dst node; fp8 feat gather.
__global__ __launch_bounds__(256) void gat_agg(const int* __restrict__ offs,
                                               const int* __restrict__ csrc,
                                               const unsigned char* __restrict__ featq,
                                               const float* __restrict__ el,
                                               const float* __restrict__ er,
                                               const float* __restrict__ bias,
                                               const unsigned short* __restrict__ hres,
                                               unsigned short* __restrict__ hout,
                                               float* __restrict__ partial, int N, int mode) {
  __shared__ float psum[4][256];
  const int wave = threadIdx.x >> 6;
  const int lane = threadIdx.x & 63;
  const int hh = lane & 7;      // head for softmax stats (8 slots x 8 heads)
  const int slot = lane >> 3;
  const int epair = lane >> 5;  // phase 2: which edge of the pair
  const int l32 = lane & 31;    // phase 2: feature block l32*8 .. +7
  const int fh = l32 >> 2;      // phase 2: head of my feature block
  const float R = 1.442695041f; // log2(e)

  float bv[8];
  {
    float4 blo = *(const float4*)(bias + l32 * 8);
    float4 bhi = *(const float4*)(bias + l32 * 8 + 4);
    bv[0] = blo.x; bv[1] = blo.y; bv[2] = blo.z; bv[3] = blo.w;
    bv[4] = bhi.x; bv[5] = bhi.y; bv[6] = bhi.z; bv[7] = bhi.w;
  }
  float t[8] = {};

  for (int n = blockIdx.x * 4 + wave; n < N; n += gridDim.x * 4) {
    const int o0 = offs[n];
    const int deg = offs[n + 1] - o0;
    const float er_h = er[n * 8 + hh];

    // ---- phase 1: online softmax stats
    float m = -1e30f, ssum = 0.f;
    for (int base = 0; base < deg; base += 8) {
      int idx = base + slot;
      if (idx < deg) {
        int s = csrc[o0 + idx];
        float e = lrelu(el[s * 8 + hh] + er_h);
        float mn = fmaxf(m, e);
        ssum = ssum * __expf(m - mn) + __expf(e - mn);
        m = mn;
      }
    }
#pragma unroll
    for (int d = 8; d < 64; d <<= 1) {
      float mo = __shfl_xor(m, d);
      float so = __shfl_xor(ssum, d);
      float mn = fmaxf(m, mo);
      ssum = ssum * __expf(m - mn) + so * __expf(mo - mn);
      m = mn;
    }
    float inv_denom = (ssum > 0.f) ? 1.f / ssum : 0.f;

    // phase-2 per-lane constants: alpha = exp2(e*R + bconst), bconst = log2(inv) - m*R
    const float m_f = __shfl(m, fh);
    const float inv_f = __shfl(inv_denom, fh);
    const float er_f = __shfl(er_h, fh);
    const float bconst = __builtin_amdgcn_logf(inv_f) - m_f * R;

    // ---- phase 2: 2 edges/iter, 32 lanes x 8B fp8 each
    float acc[8] = {};
    for (int j = 0; j < deg; j += 2) {
      int eidx = j + epair;
      int s = 0;
      float e = -1e30f;
      if (eidx < deg) {
        s = csrc[o0 + eidx];
        float tv = el[s * 8 + fh] + er_f;
        e = fmaxf(tv, NEG_SLOPE * tv);  // leaky-relu
      }
      float am = __builtin_amdgcn_exp2f(fmaf(e, R, bconst));
      uint2 f = *(const uint2*)(featq + (size_t)s * 256 + l32 * 8);
      f32x2 p0 = __builtin_amdgcn_cvt_pk_f32_fp8(f.x, false);
      f32x2 p1 = __builtin_amdgcn_cvt_pk_f32_fp8(f.x, true);
      f32x2 p2 = __builtin_amdgcn_cvt_pk_f32_fp8(f.y, false);
      f32x2 p3 = __builtin_amdgcn_cvt_pk_f32_fp8(f.y, true);
      acc[0] = fmaf(am, p0.x, acc[0]);
      acc[1] = fmaf(am, p0.y, acc[1]);
      acc[2] = fmaf(am, p1.x, acc[2]);
      acc[3] = fmaf(am, p1.y, acc[3]);
      acc[4] = fmaf(am, p2.x, acc[4]);
      acc[5] = fmaf(am, p2.y, acc[5]);
      acc[6] = fmaf(am, p3.x, acc[6]);
      acc[7] = fmaf(am, p3.y, acc[7]);
    }

    // combine the two 32-lane halves
#pragma unroll
    for (int k = 0; k < 8; ++k) acc[k] += __shfl_xor(acc[k], 32);

    if (lane < 32) {
      float v[8];
#pragma unroll
      for (int k = 0; k < 8; ++k) v[k] = acc[k] + bv[k];
      if (hres) {
        short8 r8 = *(const short8*)(hres + (size_t)n * 256 + l32 * 8);
#pragma unroll
        for (int k = 0; k < 8; ++k) v[k] += b2f((unsigned short)r8[k]);
      }
#pragma unroll
      for (int k = 0; k < 8; ++k) v[k] = eluf(v[k]);
      if (mode == 0) {
        short8 o;
#pragma unroll
        for (int k = 0; k < 8; ++k) o[k] = (short)f2b(v[k]);
        *(short8*)(hout + (size_t)n * 256 + l32 * 8) = o;
      } else {
#pragma unroll
        for (int k = 0; k < 8; ++k) t[k] += v[k];
      }
    }
  }

  if (mode == 1) {
    if (lane < 32) {
#pragma unroll
      for (int k = 0; k < 8; ++k) psum[wave][l32 * 8 + k] = t[k];
    }
    __syncthreads();
    int tt = threadIdx.x;
    partial[(size_t)blockIdx.x * 256 + tt] =
        psum[0][tt] + psum[1][tt] + psum[2][tt] + psum[3][tt];
  }
}

// ---------------- reduce partial column sums -> s[256]
__global__ __launch_bounds__(256) void reduce_partials(const float* __restrict__ partial,
                                                       float* __restrict__ s, int rows) {
  int t = threadIdx.x;
  float acc = 0.f;
  for (int r = blockIdx.x; r < rows; r += gridDim.x) acc += partial[(size_t)r * 256 + t];
  atomicAdd(&s[t], acc);
}

// ---------------- out[c] = (s/N) @ Wl + bl
__global__ __launch_bounds__(128) void final_linear(const float* __restrict__ s,
                                                    const float* __restrict__ Wl,
                                                    const float* __restrict__ bl,
                                                    float* __restrict__ out, float invN) {
  int c = threadIdx.x;
  float acc = 0.f;
  for (int k = 0; k < 256; ++k) acc = fmaf(s[k], Wl[k * 128 + c], acc);
  out[c] = acc * invN + bl[c];
}

extern "C" void kernel_launch(void* const* d_in, const int* in_sizes, int n_in, void* d_out,
                              int out_size, void* d_ws, size_t ws_size, hipStream_t stream) {
  const float* x  = (const float*)d_in[0];
  const int* src  = (const int*)d_in[1];
  const int* dst  = (const int*)d_in[2];
  const float* W1 = (const float*)d_in[3];
  const float* al1 = (const float*)d_in[4];
  const float* ar1 = (const float*)d_in[5];
  const float* b1 = (const float*)d_in[6];
  const float* W2 = (const float*)d_in[7];
  const float* al2 = (const float*)d_in[8];
  const float* ar2 = (const float*)d_in[9];
  const float* b2 = (const float*)d_in[10];
  const float* Wl = (const float*)d_in[11];
  const float* bl = (const float*)d_in[12];
  float* out = (float*)d_out;

  const int N = in_sizes[0] / 128;  // 50000
  const int E = in_sizes[1];        // 800000
  const int AGG_BLOCKS = 2048;

  // ---- workspace carve (deg and svec adjacent -> one memset)
  char* w = (char*)d_ws;
  unsigned char* featq = (unsigned char*)w;   w += (size_t)N * 256;      // 12.8 MB fp8
  unsigned short* h1b  = (unsigned short*)w;  w += (size_t)N * 256 * 2;  // 25.6 MB bf16
  unsigned short* B1t  = (unsigned short*)w;  w += (size_t)288 * 128 * 2;
  unsigned short* B2t  = (unsigned short*)w;  w += (size_t)288 * 256 * 2;
  float* el = (float*)w;        w += (size_t)N * 8 * 4;
  float* er = (float*)w;        w += (size_t)N * 8 * 4;
  int* offs = (int*)w;          w += (size_t)(N + 64) * 4;
  int* deg = (int*)w;           w += (size_t)N * 4;
  float* svec = (float*)w;      w += 256 * 4;
  int* cursor = (int*)w;        w += (size_t)(N + 64) * 4;
  int* csrc = (int*)w;          w += (size_t)E * 4;
  int* bsums = (int*)w;         w += 256 * 4;
  float* partial = (float*)w;   w += (size_t)AGG_BLOCKS * 256 * 4;

  const int nb = (N + 255) / 256;
  const int eb = (E + 255) / 256;
  const int gmb = (N + GBM - 1) / GBM;  // 782

  // ---- CSR build (dst-indexed); deg+svec zeroed in one memset
  hipMemsetAsync(deg, 0, (size_t)(N + 256) * 4, stream);
  deg_count<<<eb, 256, 0, stream>>>(dst, deg, E);
  scan1<<<nb, 256, 0, stream>>>(deg, offs, bsums, N);
  scan2<<<1, 256, 0, stream>>>(bsums, nb);
  scan3<<<nb, 256, 0, stream>>>(offs, bsums, cursor, N);
  scatter_edges<<<eb, 256, 0, stream>>>(src, dst, cursor, csrc, E);

  // ---- weight casts + P (el/er projection) build
  cast_w_both<<<432, 256, 0, stream>>>(W1, B1t, W2, B2t, al1, ar1, al2, ar2);

  // ---- layer 1 (A = x fp32; feat -> fp8; el/er from epilogue)
  gemm_bf16_v4<<<gmb, 256, 0, stream>>>(x, 1, B1t, featq, el, er, N, 128);
  gat_agg<<<AGG_BLOCKS, 256, 0, stream>>>(offs, csrc, featq, el, er, b1, nullptr, h1b, nullptr, N, 0);

  // ---- layer 2
  gemm_bf16_v4<<<gmb, 256, 0, stream>>>(h1b, 0, B2t, featq, el, er, N, 256);
  gat_agg<<<AGG_BLOCKS, 256, 0, stream>>>(offs, csrc, featq, el, er, b2, h1b, nullptr, partial, N, 1);

  // ---- mean over nodes, then final linear
  reduce_partials<<<64, 256, 0, stream>>>(partial, svec, AGG_BLOCKS);
  final_linear<<<1, 128, 0, stream>>>(svec, Wl, bl, out, 1.0f / (float)N);
}

// Round 7
// 398.517 us; speedup vs baseline: 1.2058x; 1.0720x over previous
//
#include <hip/hip_runtime.h>
#include <math.h>

#define NEG_SLOPE 0.2f

typedef __attribute__((ext_vector_type(8))) short short8;
typedef __attribute__((ext_vector_type(2))) float f32x2;
typedef __attribute__((ext_vector_type(4))) float f32x4;
typedef __attribute__((ext_vector_type(16))) float f32x16;

__device__ __forceinline__ float eluf(float x) { return x > 0.f ? x : expm1f(x); }
__device__ __forceinline__ unsigned short f2b(float f) {
  unsigned int u = __float_as_uint(f);
  u += 0x7FFFu + ((u >> 16) & 1u);  // RNE
  return (unsigned short)(u >> 16);
}
__device__ __forceinline__ float b2f(unsigned short h) {
  return __uint_as_float(((unsigned int)h) << 16);
}

// ---------------- weights: build extended Bt for both layers.
// B1t[288][128]: rows 0..255 = W1^T bf16; rows 256..263 = P_el (W1 . al1),
// rows 264..271 = P_er, rows 272..287 = 0.   B2t[288][256] likewise.
__global__ __launch_bounds__(256) void cast_w_both(const float* __restrict__ W1,
                                                   unsigned short* __restrict__ B1t,
                                                   const float* __restrict__ W2,
                                                   unsigned short* __restrict__ B2t,
                                                   const float* __restrict__ al1,
                                                   const float* __restrict__ ar1,
                                                   const float* __restrict__ al2,
                                                   const float* __restrict__ ar2) {
  int id = blockIdx.x * 256 + threadIdx.x;
  if (id < 128 * 256) {
    int k = id >> 8, n = id & 255;
    B1t[(size_t)n * 128 + k] = f2b(W1[id]);
    return;
  }
  id -= 128 * 256;
  if (id < 256 * 256) {
    int k = id >> 8, n = id & 255;
    B2t[(size_t)n * 256 + k] = f2b(W2[id]);
    return;
  }
  id -= 256 * 256;
  if (id < 128 * 16) {
    int k = id >> 4, h2 = id & 15;
    int h = h2 & 7;
    const float* av = (h2 < 8) ? al1 : ar1;
    float acc = 0.f;
    for (int d = 0; d < 32; ++d) acc = fmaf(W1[(size_t)k * 256 + h * 32 + d], av[h * 32 + d], acc);
    B1t[(size_t)(256 + h2) * 128 + k] = f2b(acc);
    return;
  }
  id -= 128 * 16;
  if (id < 256 * 16) {
    int k = id >> 4, h2 = id & 15;
    int h = h2 & 7;
    const float* av = (h2 < 8) ? al2 : ar2;
    float acc = 0.f;
    for (int d = 0; d < 32; ++d) acc = fmaf(W2[(size_t)k * 256 + h * 32 + d], av[h * 32 + d], acc);
    B2t[(size_t)(256 + h2) * 256 + k] = f2b(acc);
    return;
  }
  id -= 256 * 16;
  if (id < 16 * 128) {
    int k = id & 127, rr = 272 + (id >> 7);
    B1t[(size_t)rr * 128 + k] = 0;
    return;
  }
  id -= 16 * 128;
  if (id < 16 * 256) {
    int k = id & 255, rr = 272 + (id >> 8);
    B2t[(size_t)rr * 256 + k] = 0;
  }
}

// ---------------- GEMM: Cq[M][256] (fp8 e4m3) = A[M][K] @ B  (Bt[288][K] bf16).
// BM=64 x BN=256(+32 el/er cols), BK=32, 4 waves 2x2, 32x32x16 MFMA.
#define GBM 64
#define GBK 32
#define GLDK 36
__global__ __launch_bounds__(256) void gemm_bf16_v4(const void* __restrict__ Araw, int a_fp32,
                                                    const unsigned short* __restrict__ Bt,
                                                    unsigned char* __restrict__ Cq,
                                                    float* __restrict__ el, float* __restrict__ er,
                                                    int M, int K) {
  __shared__ unsigned short As[GBM][GLDK];
  __shared__ unsigned short Bs[288][GLDK];
  const int tid = threadIdx.x;
  const int wave = tid >> 6, lane = tid & 63;
  const int wm = wave >> 1, wn = wave & 1;
  const int l32 = lane & 31, lhalf = lane >> 5;
  const int row0 = blockIdx.x * GBM;

  f32x16 acc[4] = {};
  f32x16 acc4 = {};

  const int ar = tid >> 2;
  const int ac = (tid & 3) * 8;
  const bool arow_ok = (row0 + ar) < M;

  for (int kk = 0; kk < K; kk += GBK) {
    short8 av = {};
    if (arow_ok) {
      if (a_fp32) {
        const float* p = (const float*)Araw + (size_t)(row0 + ar) * K + kk + ac;
        float4 lo = *(const float4*)p;
        float4 hi = *(const float4*)(p + 4);
        av[0] = (short)f2b(lo.x); av[1] = (short)f2b(lo.y);
        av[2] = (short)f2b(lo.z); av[3] = (short)f2b(lo.w);
        av[4] = (short)f2b(hi.x); av[5] = (short)f2b(hi.y);
        av[6] = (short)f2b(hi.z); av[7] = (short)f2b(hi.w);
      } else {
        av = *(const short8*)((const unsigned short*)Araw + (size_t)(row0 + ar) * K + kk + ac);
      }
    }
    *(short8*)&As[ar][ac] = av;
    {
      const unsigned short* bp = Bt + (size_t)tid * K + kk;
      short8 b0 = *(const short8*)(bp + 0);
      short8 b1 = *(const short8*)(bp + 8);
      short8 b2 = *(const short8*)(bp + 16);
      short8 b3 = *(const short8*)(bp + 24);
      *(short8*)&Bs[tid][0] = b0;
      *(short8*)&Bs[tid][8] = b1;
      *(short8*)&Bs[tid][16] = b2;
      *(short8*)&Bs[tid][24] = b3;
    }
    if (tid < 32) {
      const unsigned short* bp = Bt + (size_t)(256 + tid) * K + kk;
      short8 b0 = *(const short8*)(bp + 0);
      short8 b1 = *(const short8*)(bp + 8);
      short8 b2 = *(const short8*)(bp + 16);
      short8 b3 = *(const short8*)(bp + 24);
      *(short8*)&Bs[256 + tid][0] = b0;
      *(short8*)&Bs[256 + tid][8] = b1;
      *(short8*)&Bs[256 + tid][16] = b2;
      *(short8*)&Bs[256 + tid][24] = b3;
    }
    __syncthreads();
#pragma unroll
    for (int s = 0; s < 2; ++s) {
      short8 af = *(short8*)&As[wm * 32 + l32][s * 16 + lhalf * 8];
#pragma unroll
      for (int t = 0; t < 4; ++t) {
        short8 bf = *(short8*)&Bs[wn * 128 + t * 32 + l32][s * 16 + lhalf * 8];
        acc[t] = __builtin_amdgcn_mfma_f32_32x32x16_bf16(af, bf, acc[t], 0, 0, 0);
      }
      if (wn == 1) {
        short8 bf = *(short8*)&Bs[256 + l32][s * 16 + lhalf * 8];
        acc4 = __builtin_amdgcn_mfma_f32_32x32x16_bf16(af, bf, acc4, 0, 0, 0);
      }
    }
    __syncthreads();
  }

#pragma unroll
  for (int t = 0; t < 4; ++t) {
    int col = wn * 128 + t * 32 + l32;
#pragma unroll
    for (int reg = 0; reg < 16; ++reg) {
      int row = wm * 32 + (reg & 3) + 8 * (reg >> 2) + 4 * lhalf;
      int r = row0 + row;
      if (r < M) {
        int pk = __builtin_amdgcn_cvt_pk_fp8_f32(acc[t][reg], acc[t][reg], 0, false);
        Cq[(size_t)r * 256 + col] = (unsigned char)(pk & 0xFF);
      }
    }
  }
  if (wn == 1 && l32 < 16) {
#pragma unroll
    for (int reg = 0; reg < 16; ++reg) {
      int row = wm * 32 + (reg & 3) + 8 * (reg >> 2) + 4 * lhalf;
      int r = row0 + row;
      if (r < M) {
        if (l32 < 8) el[r * 8 + l32] = acc4[reg];
        else er[r * 8 + (l32 - 8)] = acc4[reg];
      }
    }
  }
}

// ---------------- CSR build
__global__ void deg_count(const int* __restrict__ dst, int* __restrict__ deg, int E) {
  int i = blockIdx.x * blockDim.x + threadIdx.x;
  if (i < E) atomicAdd(&deg[dst[i]], 1);
}

__global__ __launch_bounds__(256) void scan1(const int* __restrict__ deg, int* __restrict__ offs,
                                             int* __restrict__ bsums, int n) {
  __shared__ int sh[256];
  int i = blockIdx.x * 256 + threadIdx.x;
  int v = (i < n) ? deg[i] : 0;
  sh[threadIdx.x] = v;
  __syncthreads();
  for (int d = 1; d < 256; d <<= 1) {
    int t = (threadIdx.x >= d) ? sh[threadIdx.x - d] : 0;
    __syncthreads();
    sh[threadIdx.x] += t;
    __syncthreads();
  }
  if (i < n) offs[i + 1] = sh[threadIdx.x];
  if (threadIdx.x == 255) bsums[blockIdx.x] = sh[255];
  if (i == 0) offs[0] = 0;
}

__global__ __launch_bounds__(256) void scan2(int* __restrict__ bsums, int nb) {
  __shared__ int sh[256];
  int t = threadIdx.x;
  int v = (t < nb) ? bsums[t] : 0;
  sh[t] = v;
  __syncthreads();
  for (int d = 1; d < 256; d <<= 1) {
    int tmp = (t >= d) ? sh[t - d] : 0;
    __syncthreads();
    sh[t] += tmp;
    __syncthreads();
  }
  if (t < nb) bsums[t] = (t == 0) ? 0 : sh[t - 1];
}

__global__ __launch_bounds__(256) void scan3(int* __restrict__ offs, const int* __restrict__ bsums,
                                             int* __restrict__ cursor, int n) {
  int i = blockIdx.x * 256 + threadIdx.x;
  if (i < n) {
    int v = offs[i + 1] + bsums[blockIdx.x];
    offs[i + 1] = v;
    cursor[i + 1] = v;
  }
  if (i == 0) cursor[0] = 0;
}

__global__ void scatter_edges(const int* __restrict__ src, const int* __restrict__ dst,
                              int* __restrict__ cursor, int* __restrict__ csrc, int E) {
  int i = blockIdx.x * blockDim.x + threadIdx.x;
  if (i < E) {
    int d = dst[i];
    int pos = atomicAdd(&cursor[d], 1);
    csrc[pos] = src[i];
  }
}

// ---------------- GAT aggregation: one wave per dst node; single-pass softmax
// (no max-shift: alpha = exp(e)/sum(exp(e)), identical normalization), fp8 gather.
__global__ __launch_bounds__(256) void gat_agg(const int* __restrict__ offs,
                                               const int* __restrict__ csrc,
                                               const unsigned char* __restrict__ featq,
                                               const float* __restrict__ el,
                                               const float* __restrict__ er,
                                               const float* __restrict__ bias,
                                               const unsigned short* __restrict__ hres,
                                               unsigned short* __restrict__ hout,
                                               float* __restrict__ partial, int N, int mode) {
  __shared__ float psum[4][256];
  const int wave = threadIdx.x >> 6;
  const int lane = threadIdx.x & 63;
  const int epair = lane >> 5;  // which edge of the pair
  const int l32 = lane & 31;    // feature block l32*8 .. +7
  const int fh = l32 >> 2;      // head of my feature block
  const float R = 1.442695041f; // log2(e)

  float bv[8];
  {
    float4 blo = *(const float4*)(bias + l32 * 8);
    float4 bhi = *(const float4*)(bias + l32 * 8 + 4);
    bv[0] = blo.x; bv[1] = blo.y; bv[2] = blo.z; bv[3] = blo.w;
    bv[4] = bhi.x; bv[5] = bhi.y; bv[6] = bhi.z; bv[7] = bhi.w;
  }
  float t[8] = {};

  for (int n = blockIdx.x * 4 + wave; n < N; n += gridDim.x * 4) {
    const int o0 = offs[n];
    const int deg = offs[n + 1] - o0;
    const float er_f = er[n * 8 + fh];

    float wsum = 0.f;
    float acc[8] = {};
#pragma unroll 2
    for (int j = 0; j < deg; j += 2) {
      int eidx = j + epair;
      int s = 0;
      float e = -1e30f;
      if (eidx < deg) {
        s = csrc[o0 + eidx];
        float tv = el[s * 8 + fh] + er_f;
        e = fmaxf(tv, NEG_SLOPE * tv);  // leaky-relu
      }
      float wgt = __builtin_amdgcn_exp2f(e * R);  // exp(e); 0 for pad lanes
      wsum += wgt;
      uint2 f = *(const uint2*)(featq + (size_t)s * 256 + l32 * 8);
      f32x2 p0 = __builtin_amdgcn_cvt_pk_f32_fp8(f.x, false);
      f32x2 p1 = __builtin_amdgcn_cvt_pk_f32_fp8(f.x, true);
      f32x2 p2 = __builtin_amdgcn_cvt_pk_f32_fp8(f.y, false);
      f32x2 p3 = __builtin_amdgcn_cvt_pk_f32_fp8(f.y, true);
      acc[0] = fmaf(wgt, p0.x, acc[0]);
      acc[1] = fmaf(wgt, p0.y, acc[1]);
      acc[2] = fmaf(wgt, p1.x, acc[2]);
      acc[3] = fmaf(wgt, p1.y, acc[3]);
      acc[4] = fmaf(wgt, p2.x, acc[4]);
      acc[5] = fmaf(wgt, p2.y, acc[5]);
      acc[6] = fmaf(wgt, p3.x, acc[6]);
      acc[7] = fmaf(wgt, p3.y, acc[7]);
    }

    // combine the two 32-lane halves
    wsum += __shfl_xor(wsum, 32);
#pragma unroll
    for (int k = 0; k < 8; ++k) acc[k] += __shfl_xor(acc[k], 32);

    if (lane < 32) {
      float inv = (wsum > 0.f) ? 1.f / wsum : 0.f;
      float v[8];
#pragma unroll
      for (int k = 0; k < 8; ++k) v[k] = fmaf(acc[k], inv, bv[k]);
      if (hres) {
        short8 r8 = *(const short8*)(hres + (size_t)n * 256 + l32 * 8);
#pragma unroll
        for (int k = 0; k < 8; ++k) v[k] += b2f((unsigned short)r8[k]);
      }
#pragma unroll
      for (int k = 0; k < 8; ++k) v[k] = eluf(v[k]);
      if (mode == 0) {
        short8 o;
#pragma unroll
        for (int k = 0; k < 8; ++k) o[k] = (short)f2b(v[k]);
        *(short8*)(hout + (size_t)n * 256 + l32 * 8) = o;
      } else {
#pragma unroll
        for (int k = 0; k < 8; ++k) t[k] += v[k];
      }
    }
  }

  if (mode == 1) {
    if (lane < 32) {
#pragma unroll
      for (int k = 0; k < 8; ++k) psum[wave][l32 * 8 + k] = t[k];
    }
    __syncthreads();
    int tt = threadIdx.x;
    partial[(size_t)blockIdx.x * 256 + tt] =
        psum[0][tt] + psum[1][tt] + psum[2][tt] + psum[3][tt];
  }
}

// ---------------- reduce partial column sums -> s[256]
__global__ __launch_bounds__(256) void reduce_partials(const float* __restrict__ partial,
                                                       float* __restrict__ s, int rows) {
  int t = threadIdx.x;
  float acc = 0.f;
  for (int r = blockIdx.x; r < rows; r += gridDim.x) acc += partial[(size_t)r * 256 + t];
  atomicAdd(&s[t], acc);
}

// ---------------- out[c] = (s/N) @ Wl + bl
__global__ __launch_bounds__(128) void final_linear(const float* __restrict__ s,
                                                    const float* __restrict__ Wl,
                                                    const float* __restrict__ bl,
                                                    float* __restrict__ out, float invN) {
  int c = threadIdx.x;
  float acc = 0.f;
  for (int k = 0; k < 256; ++k) acc = fmaf(s[k], Wl[k * 128 + c], acc);
  out[c] = acc * invN + bl[c];
}

extern "C" void kernel_launch(void* const* d_in, const int* in_sizes, int n_in, void* d_out,
                              int out_size, void* d_ws, size_t ws_size, hipStream_t stream) {
  const float* x  = (const float*)d_in[0];
  const int* src  = (const int*)d_in[1];
  const int* dst  = (const int*)d_in[2];
  const float* W1 = (const float*)d_in[3];
  const float* al1 = (const float*)d_in[4];
  const float* ar1 = (const float*)d_in[5];
  const float* b1 = (const float*)d_in[6];
  const float* W2 = (const float*)d_in[7];
  const float* al2 = (const float*)d_in[8];
  const float* ar2 = (const float*)d_in[9];
  const float* b2 = (const float*)d_in[10];
  const float* Wl = (const float*)d_in[11];
  const float* bl = (const float*)d_in[12];
  float* out = (float*)d_out;

  const int N = in_sizes[0] / 128;  // 50000
  const int E = in_sizes[1];        // 800000
  const int AGG_BLOCKS = 2048;

  // ---- workspace carve (deg and svec adjacent -> one memset)
  char* w = (char*)d_ws;
  unsigned char* featq = (unsigned char*)w;   w += (size_t)N * 256;      // 12.8 MB fp8
  unsigned short* h1b  = (unsigned short*)w;  w += (size_t)N * 256 * 2;  // 25.6 MB bf16
  unsigned short* B1t  = (unsigned short*)w;  w += (size_t)288 * 128 * 2;
  unsigned short* B2t  = (unsigned short*)w;  w += (size_t)288 * 256 * 2;
  float* el = (float*)w;        w += (size_t)N * 8 * 4;
  float* er = (float*)w;        w += (size_t)N * 8 * 4;
  int* offs = (int*)w;          w += (size_t)(N + 64) * 4;
  int* deg = (int*)w;           w += (size_t)N * 4;
  float* svec = (float*)w;      w += 256 * 4;
  int* cursor = (int*)w;        w += (size_t)(N + 64) * 4;
  int* csrc = (int*)w;          w += (size_t)E * 4;
  int* bsums = (int*)w;         w += 256 * 4;
  float* partial = (float*)w;   w += (size_t)AGG_BLOCKS * 256 * 4;

  const int nb = (N + 255) / 256;
  const int eb = (E + 255) / 256;
  const int gmb = (N + GBM - 1) / GBM;  // 782

  // ---- CSR build (dst-indexed); deg+svec zeroed in one memset
  hipMemsetAsync(deg, 0, (size_t)(N + 256) * 4, stream);
  deg_count<<<eb, 256, 0, stream>>>(dst, deg, E);
  scan1<<<nb, 256, 0, stream>>>(deg, offs, bsums, N);
  scan2<<<1, 256, 0, stream>>>(bsums, nb);
  scan3<<<nb, 256, 0, stream>>>(offs, bsums, cursor, N);
  scatter_edges<<<eb, 256, 0, stream>>>(src, dst, cursor, csrc, E);

  // ---- weight casts + P (el/er projection) build
  cast_w_both<<<432, 256, 0, stream>>>(W1, B1t, W2, B2t, al1, ar1, al2, ar2);

  // ---- layer 1 (A = x fp32; feat -> fp8; el/er from epilogue)
  gemm_bf16_v4<<<gmb, 256, 0, stream>>>(x, 1, B1t, featq, el, er, N, 128);
  gat_agg<<<AGG_BLOCKS, 256, 0, stream>>>(offs, csrc, featq, el, er, b1, nullptr, h1b, nullptr, N, 0);

  // ---- layer 2
  gemm_bf16_v4<<<gmb, 256, 0, stream>>>(h1b, 0, B2t, featq, el, er, N, 256);
  gat_agg<<<AGG_BLOCKS, 256, 0, stream>>>(offs, csrc, featq, el, er, b2, h1b, nullptr, partial, N, 1);

  // ---- mean over nodes, then final linear
  reduce_partials<<<64, 256, 0, stream>>>(partial, svec, AGG_BLOCKS);
  final_linear<<<1, 128, 0, stream>>>(svec, Wl, bl, out, 1.0f / (float)N);
}